// Round 25
// baseline (3656.777 us; speedup 1.0000x reference)
//
#include <hip/hip_runtime.h>
#include <math.h>

// ---------------------------------------------------------------------------
// Hierarchical bi-GRU (char bi-GRU -> word bi-GRU -> FC head).
//
// r25 = r24 (best, 3430us) + char-level dead-work elimination:
//   rows length-sorted DESC (deterministic counting sort); char GEMMs run in
//   sorted row space (sidx gather in A-staging, h-update scattered in place,
//   single h buffer); blocks whose max len <= t exit before any barrier.
//   Per-row math order unchanged -> bitwise-identical output.
// Word level (2430us) at its measured structural floor (8 variants tested).
//
//   gates = sigmoid(x@Wg_x + h@Wg_h + bg)      (x-part precomputed)
//   c     = tanh  (x@Wc_x + (r*h)@Wc_h + bc)
//   h'    = mask ? u*h + (1-u)*c : h
// ---------------------------------------------------------------------------

#define TILE 64
#define BKK 16

typedef __attribute__((ext_vector_type(8))) short bshort8;
typedef __attribute__((ext_vector_type(4))) float f32x4;

struct GemmArgs {
  int M, N, K;
  const float* A; int lda;
  const float* B;
  const float* bias;
  float* Cout; int ldc;
};

__device__ __forceinline__ float sigmoidf_(float x) { return 1.0f / (1.0f + expf(-x)); }
__device__ __forceinline__ float bf2f_(unsigned short u) {
  return __uint_as_float((unsigned int)u << 16);
}
__device__ __forceinline__ unsigned short f2bf_(float f) {
  const unsigned int u = __float_as_uint(f);
  return (unsigned short)((u + 0x7FFFu + ((u >> 16) & 1u)) >> 16);
}

// --------------------------- fp32 64x64 tile GEMM (stage A only) ------------
__global__ __launch_bounds__(256) void gemm_k(GemmArgs p) {
  __shared__ float As[BKK][TILE];
  __shared__ float Bs[BKK][TILE];
  const int tid = threadIdx.x;
  const int tx = tid & 15, ty = tid >> 4;
  const int m0 = blockIdx.y * TILE, n0 = blockIdx.x * TILE;
  const int la_r = tid >> 2, la_k = (tid & 3) << 2;
  const int lb_k = tid >> 4, lb_n = (tid & 15) << 2;

  float acc[4][4] = {};

  for (int k0 = 0; k0 < p.K; k0 += BKK) {
    const int m = m0 + la_r;
    const int k = k0 + la_k;
    float4 av = *reinterpret_cast<const float4*>(p.A + (size_t)m * p.lda + k);
    As[la_k + 0][la_r] = av.x;
    As[la_k + 1][la_r] = av.y;
    As[la_k + 2][la_r] = av.z;
    As[la_k + 3][la_r] = av.w;
    float4 bv = *reinterpret_cast<const float4*>(p.B + (size_t)(k0 + lb_k) * p.N + n0 + lb_n);
    *reinterpret_cast<float4*>(&Bs[lb_k][lb_n]) = bv;
    __syncthreads();
#pragma unroll
    for (int kk = 0; kk < BKK; ++kk) {
      float4 a = *reinterpret_cast<const float4*>(&As[kk][ty << 2]);
      float4 b = *reinterpret_cast<const float4*>(&Bs[kk][tx << 2]);
      acc[0][0] += a.x * b.x; acc[0][1] += a.x * b.y; acc[0][2] += a.x * b.z; acc[0][3] += a.x * b.w;
      acc[1][0] += a.y * b.x; acc[1][1] += a.y * b.y; acc[1][2] += a.y * b.z; acc[1][3] += a.y * b.w;
      acc[2][0] += a.z * b.x; acc[2][1] += a.z * b.y; acc[2][2] += a.z * b.z; acc[2][3] += a.z * b.w;
      acc[3][0] += a.w * b.x; acc[3][1] += a.w * b.y; acc[3][2] += a.w * b.z; acc[3][3] += a.w * b.w;
    }
    __syncthreads();
  }

  const int rbase = m0 + (ty << 2);
  const int cbase = n0 + (tx << 2);
#pragma unroll
  for (int i = 0; i < 4; ++i) {
    const int row = rbase + i;
#pragma unroll
    for (int j = 0; j < 4; ++j) {
      const int col = cbase + j;
      p.Cout[(size_t)row * p.ldc + col] = acc[i][j] + p.bias[col];
    }
  }
}

// fp32 -> bf16 (RNE) weight conversion
__global__ __launch_bounds__(256) void wconv_k(const float* __restrict__ src,
                                               unsigned short* __restrict__ dst,
                                               int n) {
  const int i = blockIdx.x * 256 + threadIdx.x;
  if (i < n) dst[i] = f2bf_(src[i]);
}

// ---------------------------------------------------------------------------
// Stable counting sort by length, DESCENDING (deterministic, r6-proven).
// sidx[rank] = original row; rank = #{len > L} + #{j < i : len[j] == L}.
// ---------------------------------------------------------------------------
template<int N, int MAXL>
__global__ __launch_bounds__(256) void sort_len_k(const int* __restrict__ lens,
                                                  int* __restrict__ sidx) {
  __shared__ int l_s[N];
  __shared__ int hist[MAXL + 1];
  __shared__ int pref[MAXL + 1];
  const int tid = threadIdx.x;
  for (int i = tid; i < N; i += 256) l_s[i] = lens[i];
  for (int i = tid; i <= MAXL; i += 256) hist[i] = 0;
  __syncthreads();
  for (int i = tid; i < N; i += 256) atomicAdd(&hist[l_s[i]], 1);
  __syncthreads();
  if (tid == 0) {
    pref[MAXL] = 0;
    for (int L = MAXL - 1; L >= 0; --L) pref[L] = pref[L + 1] + hist[L + 1];
  }
  __syncthreads();
  for (int i = tid; i < N; i += 256) {
    const int L = l_s[i];
    int c = 0;
    for (int j = 0; j < i; ++j) c += (l_s[j] == L) ? 1 : 0;
    sidx[pref[L] + c] = i;
  }
}

// ---------------------------------------------------------------------------
// Unified GEMM via bf16 MFMA. BM=64 rows, BN cols, BK=32, 256 thr = 4 waves.
// AM: 0 = plain rows; 1 = (r*h) rows; 2 = gathered rows Ain[arows[row]];
//     3 = concat char-state rows (k<512: row, k>=512: 2048+row).
// EM: 0 = char gate (sigmoid + XT[seqs]); 1 = char cand (tanh + masked
//     h-update); 2 = +XT[cidx[row]]; 3 = +bias[col].
// SRT: char rows length-sorted via sidx; block exits if max len <= t;
//      A rows gathered through sidx; EM=1 h read/write scattered IN PLACE.
// Fragment maps m89-verified.
// ---------------------------------------------------------------------------
template<int BN, int AM, int EM, bool SRT = false>
__global__ __launch_bounds__(256) void cgemm_mfma(
    const float* __restrict__ Ain, int lda,
    const float* __restrict__ G,          // AM=1 r-gates / EM=1 u-gates [M][1024]
    const unsigned short* __restrict__ Bw,// bf16 weights [K][ldb]
    int ldb, int K,
    const float* __restrict__ XT, int ldxt,
    const int* __restrict__ seqs,         // EM<2: [2048][16]
    const int* __restrict__ lens,         // EM<2: [2048]
    int t,
    const int* __restrict__ arows,        // AM=2 gather indices
    const int* __restrict__ cidx,         // EM=2 table indices
    const float* __restrict__ Hin,        // EM=1: h
    const int* __restrict__ sidx,         // SRT: [2048] sorted row ids
    float* __restrict__ Cout, int ldc) {
  __shared__ unsigned short As[64][40];
  __shared__ unsigned short Bs[BN][40];
  __shared__ int xo_s[64];
  __shared__ int msk_s[64];
  __shared__ int ar_s[64];

  const int tid = threadIdx.x;
  const int m0 = blockIdx.y * 64;
  const int n0 = blockIdx.x * BN;

  if constexpr (SRT) {
    // sorted desc -> first row of block holds the block max length
    if (t >= lens[sidx[m0 & 2047]]) return;   // uniform, before any barrier
  }

  if (tid < 64) {
    const int grow = m0 + tid;
    if constexpr (EM == 2) {
      xo_s[tid] = cidx[grow] * ldxt;
      msk_s[tid] = 1;
    } else if constexpr (EM == 3) {
      xo_s[tid] = 0;
      msk_s[tid] = 1;
    } else {
      int us = grow & 2047;
      if constexpr (SRT) us = sidx[us];
      ar_s[tid] = us + ((grow >= 2048) ? 2048 : 0);
      const int len = lens[us];
      const bool dir = grow >= 2048;
      int pos = dir ? (len - 1 - t) : t;
      pos = pos < 0 ? 0 : (pos > 15 ? 15 : pos);
      const int ch = seqs[us * 16 + pos];
      xo_s[tid] = ch * ldxt;
      msk_s[tid] = (t < len) ? 1 : 0;
    }
  }

  const int wid = tid >> 6, lane = tid & 63;
  const int lr = lane & 15, lk = (lane >> 4) << 3;
  constexpr int NI = BN / 64;
  const int c0w = wid * (BN / 4);

  f32x4 acc[4][NI];
#pragma unroll
  for (int mi = 0; mi < 4; ++mi)
#pragma unroll
    for (int ni = 0; ni < NI; ++ni) acc[mi][ni] = (f32x4){0.f, 0.f, 0.f, 0.f};

  const int arow = tid >> 2;
  const int akoff = (tid & 3) << 3;
  int agrow = m0 + arow;
  if constexpr (AM == 2) agrow = arows[agrow];
  if constexpr (SRT) {
    const int d = (agrow >= 2048) ? 2048 : 0;
    agrow = sidx[agrow & 2047] + d;
  }

  for (int k0 = 0; k0 < K; k0 += 32) {
    {
      const int k = k0 + akoff;
      const float* ap;
      if constexpr (AM == 3) {
        ap = (k < 512) ? (Ain + (size_t)(m0 + arow) * 512 + k)
                       : (Ain + (size_t)(2048 + m0 + arow) * 512 + (k - 512));
      } else {
        ap = Ain + (size_t)agrow * lda + k;
      }
      float4 a0 = *reinterpret_cast<const float4*>(ap);
      float4 a1 = *reinterpret_cast<const float4*>(ap + 4);
      if constexpr (AM == 1) {  // A = r * h   (G indexed in sorted/grid space)
        const float* gp = G + (size_t)(m0 + arow) * 1024 + k0 + akoff;
        float4 g0 = *reinterpret_cast<const float4*>(gp);
        float4 g1 = *reinterpret_cast<const float4*>(gp + 4);
        a0.x *= g0.x; a0.y *= g0.y; a0.z *= g0.z; a0.w *= g0.w;
        a1.x *= g1.x; a1.y *= g1.y; a1.z *= g1.z; a1.w *= g1.w;
      }
      bshort8 av;
      av[0] = (short)f2bf_(a0.x); av[1] = (short)f2bf_(a0.y);
      av[2] = (short)f2bf_(a0.z); av[3] = (short)f2bf_(a0.w);
      av[4] = (short)f2bf_(a1.x); av[5] = (short)f2bf_(a1.y);
      av[6] = (short)f2bf_(a1.z); av[7] = (short)f2bf_(a1.w);
      *reinterpret_cast<bshort8*>(&As[arow][akoff]) = av;
    }
    if (BN == 128 || tid < 128) {
      const int bc0 = (BN == 128) ? ((tid & 31) << 2) : ((tid & 15) << 2);
      const int bk0 = (BN == 128) ? ((tid >> 5) << 2) : ((tid >> 4) << 2);
      ushort4 b0 = *reinterpret_cast<const ushort4*>(Bw + (size_t)(k0 + bk0 + 0) * ldb + n0 + bc0);
      ushort4 b1 = *reinterpret_cast<const ushort4*>(Bw + (size_t)(k0 + bk0 + 1) * ldb + n0 + bc0);
      ushort4 b2 = *reinterpret_cast<const ushort4*>(Bw + (size_t)(k0 + bk0 + 2) * ldb + n0 + bc0);
      ushort4 b3 = *reinterpret_cast<const ushort4*>(Bw + (size_t)(k0 + bk0 + 3) * ldb + n0 + bc0);
      ushort4 w;
      w.x = b0.x; w.y = b1.x; w.z = b2.x; w.w = b3.x;
      *reinterpret_cast<ushort4*>(&Bs[bc0 + 0][bk0]) = w;
      w.x = b0.y; w.y = b1.y; w.z = b2.y; w.w = b3.y;
      *reinterpret_cast<ushort4*>(&Bs[bc0 + 1][bk0]) = w;
      w.x = b0.z; w.y = b1.z; w.z = b2.z; w.w = b3.z;
      *reinterpret_cast<ushort4*>(&Bs[bc0 + 2][bk0]) = w;
      w.x = b0.w; w.y = b1.w; w.z = b2.w; w.w = b3.w;
      *reinterpret_cast<ushort4*>(&Bs[bc0 + 3][bk0]) = w;
    }
    __syncthreads();

    bshort8 af[4];
#pragma unroll
    for (int mi = 0; mi < 4; ++mi)
      af[mi] = *reinterpret_cast<const bshort8*>(&As[mi * 16 + lr][lk]);
#pragma unroll
    for (int ni = 0; ni < NI; ++ni) {
      const bshort8 bf = *reinterpret_cast<const bshort8*>(&Bs[c0w + ni * 16 + lr][lk]);
#pragma unroll
      for (int mi = 0; mi < 4; ++mi)
        acc[mi][ni] = __builtin_amdgcn_mfma_f32_16x16x32_bf16(af[mi], bf, acc[mi][ni], 0, 0, 0);
    }
    __syncthreads();
  }

  const int rq = lane >> 4;
#pragma unroll
  for (int mi = 0; mi < 4; ++mi) {
#pragma unroll
    for (int ni = 0; ni < NI; ++ni) {
#pragma unroll
      for (int reg = 0; reg < 4; ++reg) {
        const int lrow = mi * 16 + rq * 4 + reg;
        const int grow = m0 + lrow;
        const int col = n0 + c0w + ni * 16 + lr;
        const float v = acc[mi][ni][reg];
        if constexpr (EM == 0) {
          Cout[(size_t)grow * ldc + col] = sigmoidf_(v + XT[xo_s[lrow] + col]);
        } else if constexpr (EM == 1) {
          const int rowA = SRT ? ar_s[lrow] : grow;   // in-place scatter
          const float cv = tanhf(v + XT[xo_s[lrow] + col]);
          const float u = G[(size_t)grow * 1024 + 512 + col];
          const float h = Hin[(size_t)rowA * 512 + col];
          Cout[(size_t)rowA * ldc + col] = msk_s[lrow] ? (u * h + (1.0f - u) * cv) : h;
        } else if constexpr (EM == 2) {
          Cout[(size_t)grow * ldc + col] = v + XT[xo_s[lrow] + col];
        } else { // EM == 3: + bias
          Cout[(size_t)grow * ldc + col] = v + XT[col];
        }
      }
    }
  }
}

// ---------------------------------------------------------------------------
// Fused persistent word GRU, bf16 weights (R=2, 256 blocks x 256 threads,
// row-major wave-coalesced weight loads; per-step context in registers).
// ---------------------------------------------------------------------------
template<int R, int NU, int TT>
__global__ __launch_bounds__(256) void gru_word_bf(
    const unsigned short* __restrict__ Whg,  // [512,1024] bf16
    const unsigned short* __restrict__ Whc,  // [512,512]  bf16
    const float* __restrict__ Xg,            // [NU*TT,1024] (bias folded)
    const float* __restrict__ Xc,            // [NU*TT,512]
    const int*   __restrict__ lens,          // [NU]
    float* __restrict__ Hout)                // [2*NU, 512]
{
  __shared__ float h_s [R][512];
  __shared__ float rh_s[R][512];
  __shared__ float u_s [R][512];

  const int tid  = threadIdx.x;
  const int row0 = blockIdx.x * R;
  const int us0  = row0 & (NU - 1);
  const bool bw  = row0 >= NU;

  for (int i = tid; i < R * 512; i += 256) h_s[i >> 9][i & 511] = 0.0f;
  int lenr[R];
#pragma unroll
  for (int r = 0; r < R; ++r) lenr[r] = lens[us0 + r];
  __syncthreads();

  const int c0 = tid << 2;   // phase-1: 4 gate cols of 1024
  const int c2 = tid << 1;   // phase-2: 2 cand cols of 512

  for (int t = 0; t < TT; ++t) {
    int xog[R], xoc[R], msk[R];
#pragma unroll
    for (int r = 0; r < R; ++r) {
      int pos = bw ? (lenr[r] - 1 - t) : t;
      pos = pos < 0 ? 0 : (pos > TT - 1 ? TT - 1 : pos);
      const int xr = (us0 + r) * TT + pos;
      xog[r] = xr * 1024;
      xoc[r] = xr * 512;
      msk[r] = (t < lenr[r]) ? 1 : 0;
    }

    // ---- phase 1: gates = sigmoid(h @ Whg + Xg); rh / u -> LDS ----
    float4 acc[R];
#pragma unroll
    for (int r = 0; r < R; ++r) acc[r] = make_float4(0.f, 0.f, 0.f, 0.f);
#pragma unroll 2
    for (int k0 = 0; k0 < 512; k0 += 4) {
      ushort4 wu[4];
#pragma unroll
      for (int i = 0; i < 4; ++i)
        wu[i] = *reinterpret_cast<const ushort4*>(Whg + (size_t)(k0 + i) * 1024 + c0);
      float4 hv[R];
#pragma unroll
      for (int r = 0; r < R; ++r)
        hv[r] = *reinterpret_cast<const float4*>(&h_s[r][k0]);
#pragma unroll
      for (int i = 0; i < 4; ++i) {
        const float wx = bf2f_(wu[i].x), wy = bf2f_(wu[i].y);
        const float wz = bf2f_(wu[i].z), ww = bf2f_(wu[i].w);
#pragma unroll
        for (int r = 0; r < R; ++r) {
          const float h = (i == 0) ? hv[r].x : (i == 1) ? hv[r].y : (i == 2) ? hv[r].z : hv[r].w;
          acc[r].x += h * wx; acc[r].y += h * wy;
          acc[r].z += h * wz; acc[r].w += h * ww;
        }
      }
    }
#pragma unroll
    for (int r = 0; r < R; ++r) {
      const float4 x = *reinterpret_cast<const float4*>(Xg + xog[r] + c0);
      float4 g;
      g.x = sigmoidf_(acc[r].x + x.x);
      g.y = sigmoidf_(acc[r].y + x.y);
      g.z = sigmoidf_(acc[r].z + x.z);
      g.w = sigmoidf_(acc[r].w + x.w);
      if (c0 < 512) {        // r-gate cols -> rh = r * h
        const float4 hh = *reinterpret_cast<const float4*>(&h_s[r][c0]);
        rh_s[r][c0 + 0] = g.x * hh.x;
        rh_s[r][c0 + 1] = g.y * hh.y;
        rh_s[r][c0 + 2] = g.z * hh.z;
        rh_s[r][c0 + 3] = g.w * hh.w;
      } else {               // u-gate cols
        u_s[r][c0 - 512 + 0] = g.x;
        u_s[r][c0 - 512 + 1] = g.y;
        u_s[r][c0 - 512 + 2] = g.z;
        u_s[r][c0 - 512 + 3] = g.w;
      }
    }
    __syncthreads();

    // ---- phase 2: c = tanh(rh @ Whc + Xc); h' = mask ? u*h+(1-u)*c : h ----
    float2 acc2[R];
#pragma unroll
    for (int r = 0; r < R; ++r) acc2[r] = make_float2(0.f, 0.f);
#pragma unroll 2
    for (int k0 = 0; k0 < 512; k0 += 4) {
      ushort2 wu[4];
#pragma unroll
      for (int i = 0; i < 4; ++i)
        wu[i] = *reinterpret_cast<const ushort2*>(Whc + (size_t)(k0 + i) * 512 + c2);
      float4 rv[R];
#pragma unroll
      for (int r = 0; r < R; ++r)
        rv[r] = *reinterpret_cast<const float4*>(&rh_s[r][k0]);
#pragma unroll
      for (int i = 0; i < 4; ++i) {
        const float wx = bf2f_(wu[i].x), wy = bf2f_(wu[i].y);
#pragma unroll
        for (int r = 0; r < R; ++r) {
          const float rvv = (i == 0) ? rv[r].x : (i == 1) ? rv[r].y : (i == 2) ? rv[r].z : rv[r].w;
          acc2[r].x += rvv * wx; acc2[r].y += rvv * wy;
        }
      }
    }
#pragma unroll
    for (int r = 0; r < R; ++r) {
      const float2 x = *reinterpret_cast<const float2*>(Xc + xoc[r] + c2);
      const float cx = tanhf(acc2[r].x + x.x);
      const float cy = tanhf(acc2[r].y + x.y);
      if (msk[r]) {
        const float ux = u_s[r][c2], uy = u_s[r][c2 + 1];
        const float hx = h_s[r][c2], hy = h_s[r][c2 + 1];
        h_s[r][c2]     = ux * hx + (1.0f - ux) * cx;
        h_s[r][c2 + 1] = uy * hy + (1.0f - uy) * cy;
      }
    }
    __syncthreads();
  }

  for (int i = tid; i < R * 512; i += 256)
    Hout[(size_t)(row0 + (i >> 9)) * 512 + (i & 511)] = h_s[i >> 9][i & 511];
}

// FC head
__global__ __launch_bounds__(64) void head_k(const float* __restrict__ Hw,
                                             const float* __restrict__ W1,
                                             const float* __restrict__ b1,
                                             const float* __restrict__ W2,
                                             const float* __restrict__ b2,
                                             float* __restrict__ out) {
  __shared__ float s[1024];
  __shared__ float hid[64];
  const int b = blockIdx.x;
  const int tid = threadIdx.x;
  for (int k = tid; k < 512; k += 64) {
    s[k]       = Hw[(size_t)b * 512 + k];
    s[512 + k] = Hw[(size_t)(256 + b) * 512 + k];
  }
  __syncthreads();
  float acc = b1[tid];
  for (int k = 0; k < 1024; ++k) acc += s[k] * W1[k * 64 + tid];
  acc = acc > 0.0f ? acc : 0.2f * acc;
  hid[tid] = acc;
  __syncthreads();
  if (tid < 2) {
    float a = b2[tid];
    for (int k = 0; k < 64; ++k) a += hid[k] * W2[k * 2 + tid];
    out[b * 2 + tid] = a;
  }
}

extern "C" void kernel_launch(void* const* d_in, const int* in_sizes, int n_in,
                              void* d_out, int out_size, void* d_ws, size_t ws_size,
                              hipStream_t stream) {
  const int*   charseqs      = (const int*)d_in[0];
  const int*   charseq_lens  = (const int*)d_in[1];
  const int*   charseq_ids   = (const int*)d_in[2];
  const int*   word_ids      = (const int*)d_in[3];
  const int*   sentence_lens = (const int*)d_in[4];
  const float* char_emb      = (const float*)d_in[5];
  const float* word_emb      = (const float*)d_in[6];
  const float* Wg_c          = (const float*)d_in[7];
  const float* bg_c          = (const float*)d_in[8];
  const float* Wc_c          = (const float*)d_in[9];
  const float* bc_c          = (const float*)d_in[10];
  const float* Wg_w          = (const float*)d_in[11];
  const float* bg_w          = (const float*)d_in[12];
  const float* Wc_w          = (const float*)d_in[13];
  const float* bc_w          = (const float*)d_in[14];
  const float* W1            = (const float*)d_in[15];
  const float* b1            = (const float*)d_in[16];
  const float* W2            = (const float*)d_in[17];
  const float* b2            = (const float*)d_in[18];
  float* out = (float*)d_out;

  float* ws = (float*)d_ws;
  size_t off = 0;
  auto alloc = [&](size_t n) { float* p = ws + off; off += n; return p; };
  float* XTABg = alloc(256 * 1024);
  float* XTABc = alloc(256 * 512);
  float* Hc    = alloc((size_t)4096 * 512);   // char h state (in-place)
  float* Gc    = alloc((size_t)4096 * 1024);
  float* CTABg = alloc((size_t)2048 * 1024);
  float* CTABc = alloc((size_t)2048 * 512);
  float* XWg   = alloc((size_t)16384 * 1024);
  float* XWc   = alloc((size_t)16384 * 512);
  float* Hw    = alloc(512 * 512);
  unsigned short* WhgBF = (unsigned short*)alloc(512 * 1024 / 2);  // word gate h-part
  unsigned short* WhcBF = (unsigned short*)alloc(512 * 512 / 2);   // word cand h-part
  unsigned short* WgcBF = (unsigned short*)alloc(512 * 1024 / 2);  // char gate h-part
  unsigned short* WccBF = (unsigned short*)alloc(512 * 512 / 2);   // char cand h-part
  unsigned short* WgwBF = (unsigned short*)alloc(256 * 1024 / 2);  // word gate emb-part
  unsigned short* WcwBF = (unsigned short*)alloc(256 * 512 / 2);   // word cand emb-part
  unsigned short* WgsBF = (unsigned short*)alloc(1024 * 1024 / 2); // word gate cstate-part
  unsigned short* WcsBF = (unsigned short*)alloc(1024 * 512 / 2);  // word cand cstate-part
  int* sidx_c = (int*)alloc(2048);

  hipMemsetAsync(Hc, 0, (size_t)4096 * 512 * sizeof(float), stream);

  // --- Stage 0: sort + bf16 weight conversions ---
  sort_len_k<2048, 16><<<1, 256, 0, stream>>>(charseq_lens, sidx_c);
  wconv_k<<<(512 * 1024 + 255) / 256, 256, 0, stream>>>(
      Wg_w + (size_t)1280 * 1024, WhgBF, 512 * 1024);
  wconv_k<<<(512 * 512 + 255) / 256, 256, 0, stream>>>(
      Wc_w + (size_t)1280 * 512, WhcBF, 512 * 512);
  wconv_k<<<(512 * 1024 + 255) / 256, 256, 0, stream>>>(
      Wg_c + 128 * 1024, WgcBF, 512 * 1024);
  wconv_k<<<(512 * 512 + 255) / 256, 256, 0, stream>>>(
      Wc_c + 128 * 512, WccBF, 512 * 512);
  wconv_k<<<(256 * 1024 + 255) / 256, 256, 0, stream>>>(
      Wg_w + (size_t)1024 * 1024, WgwBF, 256 * 1024);
  wconv_k<<<(256 * 512 + 255) / 256, 256, 0, stream>>>(
      Wc_w + (size_t)1024 * 512, WcwBF, 256 * 512);
  wconv_k<<<(1024 * 1024 + 255) / 256, 256, 0, stream>>>(
      Wg_w, WgsBF, 1024 * 1024);
  wconv_k<<<(1024 * 512 + 255) / 256, 256, 0, stream>>>(
      Wc_w, WcsBF, 1024 * 512);

  // --- Stage A: char x-part tables (fp32, tiny) ---
  {
    GemmArgs a{}; a.M = 256; a.N = 1024; a.K = 128;
    a.A = char_emb; a.lda = 128; a.B = Wg_c; a.bias = bg_c; a.Cout = XTABg; a.ldc = 1024;
    gemm_k<<<dim3(1024 / TILE, 256 / TILE), 256, 0, stream>>>(a);
    GemmArgs c{}; c.M = 256; c.N = 512; c.K = 128;
    c.A = char_emb; c.lda = 128; c.B = Wc_c; c.bias = bc_c; c.Cout = XTABc; c.ldc = 512;
    gemm_k<<<dim3(512 / TILE, 256 / TILE), 256, 0, stream>>>(c);
  }

  // --- Stage B: char bi-GRU, MFMA bf16 GEMM loop (sorted rows, in-place h,
  //              block early-exit past max len) ---
  for (int t = 0; t < 16; ++t) {
    cgemm_mfma<128, 0, 0, true><<<dim3(1024 / 128, 4096 / 64), 256, 0, stream>>>(
        Hc, 512, nullptr, WgcBF, 1024, 512, XTABg, 1024,
        charseqs, charseq_lens, t, nullptr, nullptr, nullptr, sidx_c, Gc, 1024);
    cgemm_mfma<64, 1, 1, true><<<dim3(512 / 64, 4096 / 64), 256, 0, stream>>>(
        Hc, 512, Gc, WccBF, 512, 512, XTABc, 512,
        charseqs, charseq_lens, t, nullptr, nullptr, Hc, sidx_c, Hc, 512);
  }
  // Hc holds final char states in ORIGINAL row layout (in-place scatter)

  // --- Stage C: per-wordform x-part (bf16 MFMA, AM=3/EM=3) ---
  {
    cgemm_mfma<128, 3, 3><<<dim3(1024 / 128, 2048 / 64), 256, 0, stream>>>(
        Hc, 512, nullptr, WgsBF, 1024, 1024, bg_w, 0,
        nullptr, nullptr, 0, nullptr, nullptr, nullptr, nullptr, CTABg, 1024);
    cgemm_mfma<64, 3, 3><<<dim3(512 / 64, 2048 / 64), 256, 0, stream>>>(
        Hc, 512, nullptr, WcsBF, 512, 1024, bc_w, 0,
        nullptr, nullptr, 0, nullptr, nullptr, nullptr, nullptr, CTABc, 512);
  }

  // --- Stage D: word-emb x-part + CTAB gather (bf16 MFMA) ---
  {
    cgemm_mfma<128, 2, 2><<<dim3(1024 / 128, 16384 / 64), 256, 0, stream>>>(
        word_emb, 256, nullptr, WgwBF, 1024, 256, CTABg, 1024,
        nullptr, nullptr, 0, word_ids, charseq_ids, nullptr, nullptr, XWg, 1024);
    cgemm_mfma<64, 2, 2><<<dim3(512 / 64, 16384 / 64), 256, 0, stream>>>(
        word_emb, 256, nullptr, WcwBF, 512, 256, CTABc, 512,
        nullptr, nullptr, 0, word_ids, charseq_ids, nullptr, nullptr, XWc, 512);
  }

  // --- Stage E: fused word bi-GRU, bf16 weights (R=2, 256 blocks x 256 thr) ---
  gru_word_bf<2, 256, 64><<<256, 256, 0, stream>>>(
      WhgBF, WhcBF, XWg, XWc, sentence_lens, Hw);

  // --- Stage F: FC head ---
  head_k<<<256, 64, 0, stream>>>(Hw, W1, b1, W2, b2, out);
}

// Round 26
// 3425.821 us; speedup vs baseline: 1.0674x; 1.0674x over previous
//
#include <hip/hip_runtime.h>
#include <math.h>

// ---------------------------------------------------------------------------
// Hierarchical bi-GRU (char bi-GRU -> word bi-GRU -> FC head).
//
// r26 = r24 VERBATIM (measured session best: 3430us, absmax 1.2e-4).
// r25's sorted/early-exit char loop regressed (O(N^2) sort rank + indirection
// > masked-FLOP savings) and is reverted.
//
// Final structure:
//   Stage A: char x-part tables (fp32 64x64 gemm, tiny)
//   Stage B: char bi-GRU as bf16-MFMA GEMM loop (16 steps x {gate,cand})
//   Stage C: per-wordform x-part (bf16 MFMA, AM=3 concat rows)
//   Stage D: word-emb x-part + CTAB gather (bf16 MFMA, AM=2/EM=2)
//   Stage E: word bi-GRU persistent bf16-VALU kernel (R=2, 256x256,
//            row-major wave-coalesced weights -- structural floor 2430us)
//   Stage F: FC head
//
//   gates = sigmoid(x@Wg_x + h@Wg_h + bg)      (x-part precomputed)
//   c     = tanh  (x@Wc_x + (r*h)@Wc_h + bc)
//   h'    = mask ? u*h + (1-u)*c : h
// ---------------------------------------------------------------------------

#define TILE 64
#define BKK 16

typedef __attribute__((ext_vector_type(8))) short bshort8;
typedef __attribute__((ext_vector_type(4))) float f32x4;

struct GemmArgs {
  int M, N, K;
  const float* A; int lda;
  const float* B;
  const float* bias;
  float* Cout; int ldc;
};

__device__ __forceinline__ float sigmoidf_(float x) { return 1.0f / (1.0f + expf(-x)); }
__device__ __forceinline__ float bf2f_(unsigned short u) {
  return __uint_as_float((unsigned int)u << 16);
}
__device__ __forceinline__ unsigned short f2bf_(float f) {
  const unsigned int u = __float_as_uint(f);
  return (unsigned short)((u + 0x7FFFu + ((u >> 16) & 1u)) >> 16);
}

// --------------------------- fp32 64x64 tile GEMM (stage A only) ------------
__global__ __launch_bounds__(256) void gemm_k(GemmArgs p) {
  __shared__ float As[BKK][TILE];
  __shared__ float Bs[BKK][TILE];
  const int tid = threadIdx.x;
  const int tx = tid & 15, ty = tid >> 4;
  const int m0 = blockIdx.y * TILE, n0 = blockIdx.x * TILE;
  const int la_r = tid >> 2, la_k = (tid & 3) << 2;
  const int lb_k = tid >> 4, lb_n = (tid & 15) << 2;

  float acc[4][4] = {};

  for (int k0 = 0; k0 < p.K; k0 += BKK) {
    const int m = m0 + la_r;
    const int k = k0 + la_k;
    float4 av = *reinterpret_cast<const float4*>(p.A + (size_t)m * p.lda + k);
    As[la_k + 0][la_r] = av.x;
    As[la_k + 1][la_r] = av.y;
    As[la_k + 2][la_r] = av.z;
    As[la_k + 3][la_r] = av.w;
    float4 bv = *reinterpret_cast<const float4*>(p.B + (size_t)(k0 + lb_k) * p.N + n0 + lb_n);
    *reinterpret_cast<float4*>(&Bs[lb_k][lb_n]) = bv;
    __syncthreads();
#pragma unroll
    for (int kk = 0; kk < BKK; ++kk) {
      float4 a = *reinterpret_cast<const float4*>(&As[kk][ty << 2]);
      float4 b = *reinterpret_cast<const float4*>(&Bs[kk][tx << 2]);
      acc[0][0] += a.x * b.x; acc[0][1] += a.x * b.y; acc[0][2] += a.x * b.z; acc[0][3] += a.x * b.w;
      acc[1][0] += a.y * b.x; acc[1][1] += a.y * b.y; acc[1][2] += a.y * b.z; acc[1][3] += a.y * b.w;
      acc[2][0] += a.z * b.x; acc[2][1] += a.z * b.y; acc[2][2] += a.z * b.z; acc[2][3] += a.z * b.w;
      acc[3][0] += a.w * b.x; acc[3][1] += a.w * b.y; acc[3][2] += a.w * b.z; acc[3][3] += a.w * b.w;
    }
    __syncthreads();
  }

  const int rbase = m0 + (ty << 2);
  const int cbase = n0 + (tx << 2);
#pragma unroll
  for (int i = 0; i < 4; ++i) {
    const int row = rbase + i;
#pragma unroll
    for (int j = 0; j < 4; ++j) {
      const int col = cbase + j;
      p.Cout[(size_t)row * p.ldc + col] = acc[i][j] + p.bias[col];
    }
  }
}

// fp32 -> bf16 (RNE) weight conversion
__global__ __launch_bounds__(256) void wconv_k(const float* __restrict__ src,
                                               unsigned short* __restrict__ dst,
                                               int n) {
  const int i = blockIdx.x * 256 + threadIdx.x;
  if (i < n) dst[i] = f2bf_(src[i]);
}

// ---------------------------------------------------------------------------
// Unified GEMM via bf16 MFMA. BM=64 rows, BN cols, BK=32, 256 thr = 4 waves.
// AM: 0 = plain rows of Ain (stride lda); 1 = (r*h) rows (G gates, lda=512);
//     2 = gathered rows Ain[arows[row]]; 3 = concat char-state rows
//         (k<512: Ain[row], k>=512: Ain[2048+row], lda=512).
// EM: 0 = char gate (sigmoid + XT[seqs-lookup]); 1 = char cand (tanh +
//     masked h-update); 2 = +XT[cidx[row]]; 3 = +bias[col] (XT=bias).
// Fragment maps m89-verified.
// ---------------------------------------------------------------------------
template<int BN, int AM, int EM>
__global__ __launch_bounds__(256) void cgemm_mfma(
    const float* __restrict__ Ain, int lda,
    const float* __restrict__ G,          // AM=1 r-gates / EM=1 u-gates [M][1024]
    const unsigned short* __restrict__ Bw,// bf16 weights [K][ldb]
    int ldb, int K,
    const float* __restrict__ XT, int ldxt,
    const int* __restrict__ seqs,         // EM<2: [2048][16]
    const int* __restrict__ lens,         // EM<2: [2048]
    int t,
    const int* __restrict__ arows,        // AM=2 gather indices
    const int* __restrict__ cidx,         // EM=2 table indices
    const float* __restrict__ Hin,        // EM=1: h
    float* __restrict__ Cout, int ldc) {
  __shared__ unsigned short As[64][40];
  __shared__ unsigned short Bs[BN][40];
  __shared__ int xo_s[64];
  __shared__ int msk_s[64];

  const int tid = threadIdx.x;
  const int m0 = blockIdx.y * 64;
  const int n0 = blockIdx.x * BN;

  if (tid < 64) {
    const int grow = m0 + tid;
    if constexpr (EM == 2) {
      xo_s[tid] = cidx[grow] * ldxt;
      msk_s[tid] = 1;
    } else if constexpr (EM == 3) {
      xo_s[tid] = 0;
      msk_s[tid] = 1;
    } else {
      const int us = grow & 2047;
      const bool dir = grow >= 2048;
      const int len = lens[us];
      int pos = dir ? (len - 1 - t) : t;
      pos = pos < 0 ? 0 : (pos > 15 ? 15 : pos);
      const int ch = seqs[us * 16 + pos];
      xo_s[tid] = ch * ldxt;
      msk_s[tid] = (t < len) ? 1 : 0;
    }
  }

  const int wid = tid >> 6, lane = tid & 63;
  const int lr = lane & 15, lk = (lane >> 4) << 3;
  constexpr int NI = BN / 64;
  const int c0w = wid * (BN / 4);

  f32x4 acc[4][NI];
#pragma unroll
  for (int mi = 0; mi < 4; ++mi)
#pragma unroll
    for (int ni = 0; ni < NI; ++ni) acc[mi][ni] = (f32x4){0.f, 0.f, 0.f, 0.f};

  const int arow = tid >> 2;
  const int akoff = (tid & 3) << 3;
  int agrow = m0 + arow;
  if constexpr (AM == 2) agrow = arows[m0 + arow];

  for (int k0 = 0; k0 < K; k0 += 32) {
    {
      const int k = k0 + akoff;
      const float* ap;
      if constexpr (AM == 3) {
        ap = (k < 512) ? (Ain + (size_t)(m0 + arow) * 512 + k)
                       : (Ain + (size_t)(2048 + m0 + arow) * 512 + (k - 512));
      } else {
        ap = Ain + (size_t)agrow * lda + k;
      }
      float4 a0 = *reinterpret_cast<const float4*>(ap);
      float4 a1 = *reinterpret_cast<const float4*>(ap + 4);
      if constexpr (AM == 1) {  // A = r * h
        const float* gp = G + (size_t)(m0 + arow) * 1024 + k0 + akoff;
        float4 g0 = *reinterpret_cast<const float4*>(gp);
        float4 g1 = *reinterpret_cast<const float4*>(gp + 4);
        a0.x *= g0.x; a0.y *= g0.y; a0.z *= g0.z; a0.w *= g0.w;
        a1.x *= g1.x; a1.y *= g1.y; a1.z *= g1.z; a1.w *= g1.w;
      }
      bshort8 av;
      av[0] = (short)f2bf_(a0.x); av[1] = (short)f2bf_(a0.y);
      av[2] = (short)f2bf_(a0.z); av[3] = (short)f2bf_(a0.w);
      av[4] = (short)f2bf_(a1.x); av[5] = (short)f2bf_(a1.y);
      av[6] = (short)f2bf_(a1.z); av[7] = (short)f2bf_(a1.w);
      *reinterpret_cast<bshort8*>(&As[arow][akoff]) = av;
    }
    if (BN == 128 || tid < 128) {
      const int bc0 = (BN == 128) ? ((tid & 31) << 2) : ((tid & 15) << 2);
      const int bk0 = (BN == 128) ? ((tid >> 5) << 2) : ((tid >> 4) << 2);
      ushort4 b0 = *reinterpret_cast<const ushort4*>(Bw + (size_t)(k0 + bk0 + 0) * ldb + n0 + bc0);
      ushort4 b1 = *reinterpret_cast<const ushort4*>(Bw + (size_t)(k0 + bk0 + 1) * ldb + n0 + bc0);
      ushort4 b2 = *reinterpret_cast<const ushort4*>(Bw + (size_t)(k0 + bk0 + 2) * ldb + n0 + bc0);
      ushort4 b3 = *reinterpret_cast<const ushort4*>(Bw + (size_t)(k0 + bk0 + 3) * ldb + n0 + bc0);
      ushort4 w;
      w.x = b0.x; w.y = b1.x; w.z = b2.x; w.w = b3.x;
      *reinterpret_cast<ushort4*>(&Bs[bc0 + 0][bk0]) = w;
      w.x = b0.y; w.y = b1.y; w.z = b2.y; w.w = b3.y;
      *reinterpret_cast<ushort4*>(&Bs[bc0 + 1][bk0]) = w;
      w.x = b0.z; w.y = b1.z; w.z = b2.z; w.w = b3.z;
      *reinterpret_cast<ushort4*>(&Bs[bc0 + 2][bk0]) = w;
      w.x = b0.w; w.y = b1.w; w.z = b2.w; w.w = b3.w;
      *reinterpret_cast<ushort4*>(&Bs[bc0 + 3][bk0]) = w;
    }
    __syncthreads();

    bshort8 af[4];
#pragma unroll
    for (int mi = 0; mi < 4; ++mi)
      af[mi] = *reinterpret_cast<const bshort8*>(&As[mi * 16 + lr][lk]);
#pragma unroll
    for (int ni = 0; ni < NI; ++ni) {
      const bshort8 bf = *reinterpret_cast<const bshort8*>(&Bs[c0w + ni * 16 + lr][lk]);
#pragma unroll
      for (int mi = 0; mi < 4; ++mi)
        acc[mi][ni] = __builtin_amdgcn_mfma_f32_16x16x32_bf16(af[mi], bf, acc[mi][ni], 0, 0, 0);
    }
    __syncthreads();
  }

  const int rq = lane >> 4;
#pragma unroll
  for (int mi = 0; mi < 4; ++mi) {
#pragma unroll
    for (int ni = 0; ni < NI; ++ni) {
#pragma unroll
      for (int reg = 0; reg < 4; ++reg) {
        const int lrow = mi * 16 + rq * 4 + reg;
        const int grow = m0 + lrow;
        const int col = n0 + c0w + ni * 16 + lr;
        const float v = acc[mi][ni][reg];
        if constexpr (EM == 0) {
          Cout[(size_t)grow * ldc + col] = sigmoidf_(v + XT[xo_s[lrow] + col]);
        } else if constexpr (EM == 1) {
          const float cv = tanhf(v + XT[xo_s[lrow] + col]);
          const float u = G[(size_t)grow * 1024 + 512 + col];
          const float h = Hin[(size_t)grow * 512 + col];
          Cout[(size_t)grow * ldc + col] = msk_s[lrow] ? (u * h + (1.0f - u) * cv) : h;
        } else if constexpr (EM == 2) {
          Cout[(size_t)grow * ldc + col] = v + XT[xo_s[lrow] + col];
        } else { // EM == 3: + bias
          Cout[(size_t)grow * ldc + col] = v + XT[col];
        }
      }
    }
  }
}

// ---------------------------------------------------------------------------
// Fused persistent word GRU, bf16 weights (R=2, 256 blocks x 256 threads,
// row-major wave-coalesced weight loads; per-step context in registers).
// ---------------------------------------------------------------------------
template<int R, int NU, int TT>
__global__ __launch_bounds__(256) void gru_word_bf(
    const unsigned short* __restrict__ Whg,  // [512,1024] bf16
    const unsigned short* __restrict__ Whc,  // [512,512]  bf16
    const float* __restrict__ Xg,            // [NU*TT,1024] (bias folded)
    const float* __restrict__ Xc,            // [NU*TT,512]
    const int*   __restrict__ lens,          // [NU]
    float* __restrict__ Hout)                // [2*NU, 512]
{
  __shared__ float h_s [R][512];
  __shared__ float rh_s[R][512];
  __shared__ float u_s [R][512];

  const int tid  = threadIdx.x;
  const int row0 = blockIdx.x * R;
  const int us0  = row0 & (NU - 1);
  const bool bw  = row0 >= NU;

  for (int i = tid; i < R * 512; i += 256) h_s[i >> 9][i & 511] = 0.0f;
  int lenr[R];
#pragma unroll
  for (int r = 0; r < R; ++r) lenr[r] = lens[us0 + r];
  __syncthreads();

  const int c0 = tid << 2;   // phase-1: 4 gate cols of 1024
  const int c2 = tid << 1;   // phase-2: 2 cand cols of 512

  for (int t = 0; t < TT; ++t) {
    int xog[R], xoc[R], msk[R];
#pragma unroll
    for (int r = 0; r < R; ++r) {
      int pos = bw ? (lenr[r] - 1 - t) : t;
      pos = pos < 0 ? 0 : (pos > TT - 1 ? TT - 1 : pos);
      const int xr = (us0 + r) * TT + pos;
      xog[r] = xr * 1024;
      xoc[r] = xr * 512;
      msk[r] = (t < lenr[r]) ? 1 : 0;
    }

    // ---- phase 1: gates = sigmoid(h @ Whg + Xg); rh / u -> LDS ----
    float4 acc[R];
#pragma unroll
    for (int r = 0; r < R; ++r) acc[r] = make_float4(0.f, 0.f, 0.f, 0.f);
#pragma unroll 2
    for (int k0 = 0; k0 < 512; k0 += 4) {
      ushort4 wu[4];
#pragma unroll
      for (int i = 0; i < 4; ++i)
        wu[i] = *reinterpret_cast<const ushort4*>(Whg + (size_t)(k0 + i) * 1024 + c0);
      float4 hv[R];
#pragma unroll
      for (int r = 0; r < R; ++r)
        hv[r] = *reinterpret_cast<const float4*>(&h_s[r][k0]);
#pragma unroll
      for (int i = 0; i < 4; ++i) {
        const float wx = bf2f_(wu[i].x), wy = bf2f_(wu[i].y);
        const float wz = bf2f_(wu[i].z), ww = bf2f_(wu[i].w);
#pragma unroll
        for (int r = 0; r < R; ++r) {
          const float h = (i == 0) ? hv[r].x : (i == 1) ? hv[r].y : (i == 2) ? hv[r].z : hv[r].w;
          acc[r].x += h * wx; acc[r].y += h * wy;
          acc[r].z += h * wz; acc[r].w += h * ww;
        }
      }
    }
#pragma unroll
    for (int r = 0; r < R; ++r) {
      const float4 x = *reinterpret_cast<const float4*>(Xg + xog[r] + c0);
      float4 g;
      g.x = sigmoidf_(acc[r].x + x.x);
      g.y = sigmoidf_(acc[r].y + x.y);
      g.z = sigmoidf_(acc[r].z + x.z);
      g.w = sigmoidf_(acc[r].w + x.w);
      if (c0 < 512) {        // r-gate cols -> rh = r * h
        const float4 hh = *reinterpret_cast<const float4*>(&h_s[r][c0]);
        rh_s[r][c0 + 0] = g.x * hh.x;
        rh_s[r][c0 + 1] = g.y * hh.y;
        rh_s[r][c0 + 2] = g.z * hh.z;
        rh_s[r][c0 + 3] = g.w * hh.w;
      } else {               // u-gate cols
        u_s[r][c0 - 512 + 0] = g.x;
        u_s[r][c0 - 512 + 1] = g.y;
        u_s[r][c0 - 512 + 2] = g.z;
        u_s[r][c0 - 512 + 3] = g.w;
      }
    }
    __syncthreads();

    // ---- phase 2: c = tanh(rh @ Whc + Xc); h' = mask ? u*h+(1-u)*c : h ----
    float2 acc2[R];
#pragma unroll
    for (int r = 0; r < R; ++r) acc2[r] = make_float2(0.f, 0.f);
#pragma unroll 2
    for (int k0 = 0; k0 < 512; k0 += 4) {
      ushort2 wu[4];
#pragma unroll
      for (int i = 0; i < 4; ++i)
        wu[i] = *reinterpret_cast<const ushort2*>(Whc + (size_t)(k0 + i) * 512 + c2);
      float4 rv[R];
#pragma unroll
      for (int r = 0; r < R; ++r)
        rv[r] = *reinterpret_cast<const float4*>(&rh_s[r][k0]);
#pragma unroll
      for (int i = 0; i < 4; ++i) {
        const float wx = bf2f_(wu[i].x), wy = bf2f_(wu[i].y);
#pragma unroll
        for (int r = 0; r < R; ++r) {
          const float rvv = (i == 0) ? rv[r].x : (i == 1) ? rv[r].y : (i == 2) ? rv[r].z : rv[r].w;
          acc2[r].x += rvv * wx; acc2[r].y += rvv * wy;
        }
      }
    }
#pragma unroll
    for (int r = 0; r < R; ++r) {
      const float2 x = *reinterpret_cast<const float2*>(Xc + xoc[r] + c2);
      const float cx = tanhf(acc2[r].x + x.x);
      const float cy = tanhf(acc2[r].y + x.y);
      if (msk[r]) {
        const float ux = u_s[r][c2], uy = u_s[r][c2 + 1];
        const float hx = h_s[r][c2], hy = h_s[r][c2 + 1];
        h_s[r][c2]     = ux * hx + (1.0f - ux) * cx;
        h_s[r][c2 + 1] = uy * hy + (1.0f - uy) * cy;
      }
    }
    __syncthreads();
  }

  for (int i = tid; i < R * 512; i += 256)
    Hout[(size_t)(row0 + (i >> 9)) * 512 + (i & 511)] = h_s[i >> 9][i & 511];
}

// FC head
__global__ __launch_bounds__(64) void head_k(const float* __restrict__ Hw,
                                             const float* __restrict__ W1,
                                             const float* __restrict__ b1,
                                             const float* __restrict__ W2,
                                             const float* __restrict__ b2,
                                             float* __restrict__ out) {
  __shared__ float s[1024];
  __shared__ float hid[64];
  const int b = blockIdx.x;
  const int tid = threadIdx.x;
  for (int k = tid; k < 512; k += 64) {
    s[k]       = Hw[(size_t)b * 512 + k];
    s[512 + k] = Hw[(size_t)(256 + b) * 512 + k];
  }
  __syncthreads();
  float acc = b1[tid];
  for (int k = 0; k < 1024; ++k) acc += s[k] * W1[k * 64 + tid];
  acc = acc > 0.0f ? acc : 0.2f * acc;
  hid[tid] = acc;
  __syncthreads();
  if (tid < 2) {
    float a = b2[tid];
    for (int k = 0; k < 64; ++k) a += hid[k] * W2[k * 2 + tid];
    out[b * 2 + tid] = a;
  }
}

extern "C" void kernel_launch(void* const* d_in, const int* in_sizes, int n_in,
                              void* d_out, int out_size, void* d_ws, size_t ws_size,
                              hipStream_t stream) {
  const int*   charseqs      = (const int*)d_in[0];
  const int*   charseq_lens  = (const int*)d_in[1];
  const int*   charseq_ids   = (const int*)d_in[2];
  const int*   word_ids      = (const int*)d_in[3];
  const int*   sentence_lens = (const int*)d_in[4];
  const float* char_emb      = (const float*)d_in[5];
  const float* word_emb      = (const float*)d_in[6];
  const float* Wg_c          = (const float*)d_in[7];
  const float* bg_c          = (const float*)d_in[8];
  const float* Wc_c          = (const float*)d_in[9];
  const float* bc_c          = (const float*)d_in[10];
  const float* Wg_w          = (const float*)d_in[11];
  const float* bg_w          = (const float*)d_in[12];
  const float* Wc_w          = (const float*)d_in[13];
  const float* bc_w          = (const float*)d_in[14];
  const float* W1            = (const float*)d_in[15];
  const float* b1            = (const float*)d_in[16];
  const float* W2            = (const float*)d_in[17];
  const float* b2            = (const float*)d_in[18];
  float* out = (float*)d_out;

  float* ws = (float*)d_ws;
  size_t off = 0;
  auto alloc = [&](size_t n) { float* p = ws + off; off += n; return p; };
  float* XTABg = alloc(256 * 1024);
  float* XTABc = alloc(256 * 512);
  float* HcA   = alloc((size_t)4096 * 512);
  float* HcB   = alloc((size_t)4096 * 512);
  float* Gc    = alloc((size_t)4096 * 1024);
  float* CTABg = alloc((size_t)2048 * 1024);
  float* CTABc = alloc((size_t)2048 * 512);
  float* XWg   = alloc((size_t)16384 * 1024);
  float* XWc   = alloc((size_t)16384 * 512);
  float* Hw    = alloc(512 * 512);
  unsigned short* WhgBF = (unsigned short*)alloc(512 * 1024 / 2);  // word gate h-part
  unsigned short* WhcBF = (unsigned short*)alloc(512 * 512 / 2);   // word cand h-part
  unsigned short* WgcBF = (unsigned short*)alloc(512 * 1024 / 2);  // char gate h-part
  unsigned short* WccBF = (unsigned short*)alloc(512 * 512 / 2);   // char cand h-part
  unsigned short* WgwBF = (unsigned short*)alloc(256 * 1024 / 2);  // word gate emb-part
  unsigned short* WcwBF = (unsigned short*)alloc(256 * 512 / 2);   // word cand emb-part
  unsigned short* WgsBF = (unsigned short*)alloc(1024 * 1024 / 2); // word gate cstate-part
  unsigned short* WcsBF = (unsigned short*)alloc(1024 * 512 / 2);  // word cand cstate-part

  hipMemsetAsync(HcA, 0, (size_t)4096 * 512 * sizeof(float), stream);

  // --- Stage 0: bf16 weight conversions ---
  wconv_k<<<(512 * 1024 + 255) / 256, 256, 0, stream>>>(
      Wg_w + (size_t)1280 * 1024, WhgBF, 512 * 1024);
  wconv_k<<<(512 * 512 + 255) / 256, 256, 0, stream>>>(
      Wc_w + (size_t)1280 * 512, WhcBF, 512 * 512);
  wconv_k<<<(512 * 1024 + 255) / 256, 256, 0, stream>>>(
      Wg_c + 128 * 1024, WgcBF, 512 * 1024);
  wconv_k<<<(512 * 512 + 255) / 256, 256, 0, stream>>>(
      Wc_c + 128 * 512, WccBF, 512 * 512);
  wconv_k<<<(256 * 1024 + 255) / 256, 256, 0, stream>>>(
      Wg_w + (size_t)1024 * 1024, WgwBF, 256 * 1024);
  wconv_k<<<(256 * 512 + 255) / 256, 256, 0, stream>>>(
      Wc_w + (size_t)1024 * 512, WcwBF, 256 * 512);
  wconv_k<<<(1024 * 1024 + 255) / 256, 256, 0, stream>>>(
      Wg_w, WgsBF, 1024 * 1024);
  wconv_k<<<(1024 * 512 + 255) / 256, 256, 0, stream>>>(
      Wc_w, WcsBF, 1024 * 512);

  // --- Stage A: char x-part tables (fp32, tiny) ---
  {
    GemmArgs a{}; a.M = 256; a.N = 1024; a.K = 128;
    a.A = char_emb; a.lda = 128; a.B = Wg_c; a.bias = bg_c; a.Cout = XTABg; a.ldc = 1024;
    gemm_k<<<dim3(1024 / TILE, 256 / TILE), 256, 0, stream>>>(a);
    GemmArgs c{}; c.M = 256; c.N = 512; c.K = 128;
    c.A = char_emb; c.lda = 128; c.B = Wc_c; c.bias = bc_c; c.Cout = XTABc; c.ldc = 512;
    gemm_k<<<dim3(512 / TILE, 256 / TILE), 256, 0, stream>>>(c);
  }

  // --- Stage B: char bi-GRU, MFMA bf16 GEMM loop ---
  float* hcur = HcA; float* hnext = HcB;
  for (int t = 0; t < 16; ++t) {
    cgemm_mfma<128, 0, 0><<<dim3(1024 / 128, 4096 / 64), 256, 0, stream>>>(
        hcur, 512, nullptr, WgcBF, 1024, 512, XTABg, 1024,
        charseqs, charseq_lens, t, nullptr, nullptr, nullptr, Gc, 1024);
    cgemm_mfma<64, 1, 1><<<dim3(512 / 64, 4096 / 64), 256, 0, stream>>>(
        hcur, 512, Gc, WccBF, 512, 512, XTABc, 512,
        charseqs, charseq_lens, t, nullptr, nullptr, hcur, hnext, 512);
    float* tmp = hcur; hcur = hnext; hnext = tmp;
  }
  // after 16 steps hcur == HcA

  // --- Stage C: per-wordform x-part (bf16 MFMA, AM=3/EM=3) ---
  {
    cgemm_mfma<128, 3, 3><<<dim3(1024 / 128, 2048 / 64), 256, 0, stream>>>(
        hcur, 512, nullptr, WgsBF, 1024, 1024, bg_w, 0,
        nullptr, nullptr, 0, nullptr, nullptr, nullptr, CTABg, 1024);
    cgemm_mfma<64, 3, 3><<<dim3(512 / 64, 2048 / 64), 256, 0, stream>>>(
        hcur, 512, nullptr, WcsBF, 512, 1024, bc_w, 0,
        nullptr, nullptr, 0, nullptr, nullptr, nullptr, CTABc, 512);
  }

  // --- Stage D: word-emb x-part + CTAB gather (bf16 MFMA) ---
  {
    cgemm_mfma<128, 2, 2><<<dim3(1024 / 128, 16384 / 64), 256, 0, stream>>>(
        word_emb, 256, nullptr, WgwBF, 1024, 256, CTABg, 1024,
        nullptr, nullptr, 0, word_ids, charseq_ids, nullptr, XWg, 1024);
    cgemm_mfma<64, 2, 2><<<dim3(512 / 64, 16384 / 64), 256, 0, stream>>>(
        word_emb, 256, nullptr, WcwBF, 512, 256, CTABc, 512,
        nullptr, nullptr, 0, word_ids, charseq_ids, nullptr, XWc, 512);
  }

  // --- Stage E: fused word bi-GRU, bf16 weights (R=2, 256 blocks x 256 thr) ---
  gru_word_bf<2, 256, 64><<<256, 256, 0, stream>>>(
      WhgBF, WhcBF, XWg, XWc, sentence_lens, Hw);

  // --- Stage F: FC head ---
  head_k<<<256, 64, 0, stream>>>(Hw, W1, b1, W2, b2, out);
}